// Round 6
// baseline (76.261 us; speedup 1.0000x reference)
//
#include <hip/hip_runtime.h>
#include <math.h>

#define Bq 512
#define Dq 256
#define MS (Bq * Dq)

typedef _Float16 f16x8 __attribute__((ext_vector_type(8)));
typedef float f32x4 __attribute__((ext_vector_type(4)));

__device__ __forceinline__ float waveReduceSum(float v) {
    #pragma unroll
    for (int off = 32; off > 0; off >>= 1)
        v += __shfl_xor(v, off, 64);
    return v;
}

__device__ __forceinline__ void split16(float x, _Float16* h, _Float16* l) {
    _Float16 hh = (_Float16)x;
    *h = hh;
    *l = (_Float16)(x - (float)hh);
}

// Kernel 1: per-row L2 norm, then build 10 f16 operand planes ([row][k],
// k-contiguous), hi/lo split where full precision is needed:
//  0 C1h 1 C1l : c1 = a(1+a^3)      (du numerator, full precision)
//  2 C2h 3 C2l : c2 = (1+a^3)^2     (nu, full precision)
//  4 Ah  5 Al  : a                  (dv main term + B1 side, full precision)
//  6 A2h 7 A2l : a^2                (B2 side + nv's a^2, full for nu)
//  8 A3h       : a^3                (small terms, hi only)
//  9 A4h       : a^4 * 64           (tiny term, scaled off fp16 subnormals)
// Also zeroes the S/V accumulators (re-poisoned workspace each iteration).
__global__ __launch_bounds__(256) void prep_kernel(
        const float* __restrict__ feat, _Float16* __restrict__ M,
        float* __restrict__ S, float* __restrict__ V) {
    int r = blockIdx.x;
    int k = threadIdx.x;
    float x = feat[r * Dq + k];
    float ss = waveReduceSum(x * x);
    __shared__ float wsum[4];
    int wid = k >> 6, lane = k & 63;
    if (lane == 0) wsum[wid] = ss;
    __syncthreads();
    float n = fmaxf(sqrtf(wsum[0] + wsum[1] + wsum[2] + wsum[3]), 1e-12f);
    float a = x / n;
    float a2 = a * a, a3 = a2 * a, a4 = a2 * a2;
    float c1 = a * (1.0f + a3);
    float c2 = (1.0f + a3) * (1.0f + a3);
    int o = r * Dq + k;
    _Float16 h, l;
    split16(c1, &h, &l); M[0 * MS + o] = h; M[1 * MS + o] = l;
    split16(c2, &h, &l); M[2 * MS + o] = h; M[3 * MS + o] = l;
    split16(a,  &h, &l); M[4 * MS + o] = h; M[5 * MS + o] = l;
    split16(a2, &h, &l); M[6 * MS + o] = h; M[7 * MS + o] = l;
    M[8 * MS + o] = (_Float16)a3;
    M[9 * MS + o] = (_Float16)(a4 * 64.0f);
    if (r == 0) {
        S[k] = 0.f; S[k + 256] = 0.f;
        V[k] = 0.f; V[k + 256] = 0.f;
    }
}

// Kernel 2: split-fp16 MFMA GEMM. 256 blocks x 256 threads; wave w of block bx
// owns the 16x16 output tile (it, jt). Per 16x16x32 k-step: 12 MFMAs
//   du : c1h*bh + c1h*bl + c1l*bh          (b = a-row of j)
//   nu : c2h*b2h + c2h*b2l + c2l*b2h
//   dv : ah*bh + ah*bl + al*bh + a3h*b2h
//   n3 : a2h * b3h        (nv = 1 + 2*n3 + n4/4096)
//   n4 : (a4*64) * (b4*64)
// Output C/D layout (m89-verified): col = lane&15 (j), row = (lane>>4)*4+reg (i).
// Epilogue: raw_s/raw_o, exp, 16-lane j-reduce, atomicAdd into S[i], V[i].
__global__ __launch_bounds__(256) void pairmm_kernel(
        const _Float16* __restrict__ M,
        float* __restrict__ S, float* __restrict__ V) {
    const int t = threadIdx.x;
    const int w = t >> 6, lane = t & 63;
    const int lr = lane & 15, lg = lane >> 4;
    const int bx = blockIdx.x;
    const int it = (bx >> 4) * 32 + (w >> 1) * 16;
    const int jt = (bx & 15) * 32 + (w & 1) * 16;
    const int offi = (it + lr) * Dq + lg * 8;
    const int offj = (jt + lr) * Dq + lg * 8;

    const _Float16* __restrict__ C1h = M;
    const _Float16* __restrict__ C1l = M + 1 * MS;
    const _Float16* __restrict__ C2h = M + 2 * MS;
    const _Float16* __restrict__ C2l = M + 3 * MS;
    const _Float16* __restrict__ Ah  = M + 4 * MS;
    const _Float16* __restrict__ Al  = M + 5 * MS;
    const _Float16* __restrict__ A2h = M + 6 * MS;
    const _Float16* __restrict__ A2l = M + 7 * MS;
    const _Float16* __restrict__ A3h = M + 8 * MS;
    const _Float16* __restrict__ A4h = M + 9 * MS;

    f32x4 du = {0.f, 0.f, 0.f, 0.f};
    f32x4 nu = {0.f, 0.f, 0.f, 0.f};
    f32x4 dv = {0.f, 0.f, 0.f, 0.f};
    f32x4 n3 = {0.f, 0.f, 0.f, 0.f};
    f32x4 n4 = {0.f, 0.f, 0.f, 0.f};

    #pragma unroll 2
    for (int kk = 0; kk < Dq; kk += 32) {
        int oi = offi + kk, oj = offj + kk;
        f16x8 c1h = *(const f16x8*)(C1h + oi);
        f16x8 c1l = *(const f16x8*)(C1l + oi);
        f16x8 c2h = *(const f16x8*)(C2h + oi);
        f16x8 c2l = *(const f16x8*)(C2l + oi);
        f16x8 ahi = *(const f16x8*)(Ah  + oi);
        f16x8 ali = *(const f16x8*)(Al  + oi);
        f16x8 a2i = *(const f16x8*)(A2h + oi);
        f16x8 a3i = *(const f16x8*)(A3h + oi);
        f16x8 a4i = *(const f16x8*)(A4h + oi);
        f16x8 ahj = *(const f16x8*)(Ah  + oj);
        f16x8 alj = *(const f16x8*)(Al  + oj);
        f16x8 a2j = *(const f16x8*)(A2h + oj);
        f16x8 a2lj = *(const f16x8*)(A2l + oj);
        f16x8 a3j = *(const f16x8*)(A3h + oj);
        f16x8 a4j = *(const f16x8*)(A4h + oj);

        du = __builtin_amdgcn_mfma_f32_16x16x32_f16(c1h, ahj,  du, 0, 0, 0);
        du = __builtin_amdgcn_mfma_f32_16x16x32_f16(c1h, alj,  du, 0, 0, 0);
        du = __builtin_amdgcn_mfma_f32_16x16x32_f16(c1l, ahj,  du, 0, 0, 0);
        nu = __builtin_amdgcn_mfma_f32_16x16x32_f16(c2h, a2j,  nu, 0, 0, 0);
        nu = __builtin_amdgcn_mfma_f32_16x16x32_f16(c2h, a2lj, nu, 0, 0, 0);
        nu = __builtin_amdgcn_mfma_f32_16x16x32_f16(c2l, a2j,  nu, 0, 0, 0);
        dv = __builtin_amdgcn_mfma_f32_16x16x32_f16(ahi, ahj,  dv, 0, 0, 0);
        dv = __builtin_amdgcn_mfma_f32_16x16x32_f16(ahi, alj,  dv, 0, 0, 0);
        dv = __builtin_amdgcn_mfma_f32_16x16x32_f16(ali, ahj,  dv, 0, 0, 0);
        dv = __builtin_amdgcn_mfma_f32_16x16x32_f16(a3i, a2j,  dv, 0, 0, 0);
        n3 = __builtin_amdgcn_mfma_f32_16x16x32_f16(a2i, a3j,  n3, 0, 0, 0);
        n4 = __builtin_amdgcn_mfma_f32_16x16x32_f16(a4i, a4j,  n4, 0, 0, 0);
    }

    const float Tinv = 1.0f / 0.07f;
    float sS[4], sV[4];
    #pragma unroll
    for (int r = 0; r < 4; ++r) {
        float nuv = fmaxf(nu[r], 0.f);
        float nvv = fmaxf(1.0f + 2.0f * n3[r] + n4[r] * (1.0f / 4096.0f), 0.f);
        float raw_s = du[r] / fmaxf(sqrtf(nuv), 1e-12f) * Tinv;
        float raw_o = dv[r] / fmaxf(sqrtf(nvv), 1e-12f) * Tinv;
        int gi = it + lg * 4 + r;
        int gj = jt + lr;
        sS[r] = raw_s;
        sV[r] = (gi == gj) ? 0.f : (expf(raw_s) + 3.0f * expf(raw_o));
    }
    #pragma unroll
    for (int r = 0; r < 4; ++r) {
        #pragma unroll
        for (int m = 1; m < 16; m <<= 1) {
            sS[r] += __shfl_xor(sS[r], m, 64);
            sV[r] += __shfl_xor(sV[r], m, 64);
        }
    }
    if (lr == 0) {
        #pragma unroll
        for (int r = 0; r < 4; ++r) {
            atomicAdd(&S[it + lg * 4 + r], sS[r]);
            atomicAdd(&V[it + lg * 4 + r], sV[r]);
        }
    }
}

// Kernel 3: loss = -(1/B) * sum_i ( S[i]/B - log(V[i]) )
__global__ __launch_bounds__(512) void final_kernel(
        const float* __restrict__ Sv, const float* __restrict__ Vv,
        float* __restrict__ out) {
    int i = threadIdx.x;
    float t = Sv[i] * (1.0f / Bq) - logf(Vv[i]);
    t = waveReduceSum(t);
    __shared__ float red[8];
    int wid = i >> 6, lane = i & 63;
    if (lane == 0) red[wid] = t;
    __syncthreads();
    if (i == 0) {
        float s = 0.f;
        #pragma unroll
        for (int w = 0; w < 8; ++w) s += red[w];
        out[0] = -s / (float)Bq;
    }
}

extern "C" void kernel_launch(void* const* d_in, const int* in_sizes, int n_in,
                              void* d_out, int out_size, void* d_ws, size_t ws_size,
                              hipStream_t stream) {
    const float* feat = (const float*)d_in[0];
    _Float16* M = (_Float16*)d_ws;                       // 10 * MS halves = 2.62 MB
    float* S = (float*)((char*)d_ws + (size_t)10 * MS * sizeof(_Float16));
    float* V = S + Bq;

    prep_kernel<<<Bq, Dq, 0, stream>>>(feat, M, S, V);
    pairmm_kernel<<<256, 256, 0, stream>>>(M, S, V);
    final_kernel<<<1, Bq, 0, stream>>>(S, V, (float*)d_out);
}

// Round 7
// 76.195 us; speedup vs baseline: 1.0009x; 1.0009x over previous
//
#include <hip/hip_runtime.h>
#include <math.h>

#define Bq 512
#define Dq 256
#define MS (Bq * Dq)

typedef _Float16 f16x8 __attribute__((ext_vector_type(8)));
typedef float f32x4 __attribute__((ext_vector_type(4)));

__device__ __forceinline__ float waveReduceSum(float v) {
    #pragma unroll
    for (int off = 32; off > 0; off >>= 1)
        v += __shfl_xor(v, off, 64);
    return v;
}

__device__ __forceinline__ void split16(float x, _Float16* h, _Float16* l) {
    _Float16 hh = (_Float16)x;
    *h = hh;
    *l = (_Float16)(x - (float)hh);
}

// Kernel 1: per-row L2 norm, then build 10 f16 operand planes ([row][k],
// k-contiguous), hi/lo split where full precision is needed. Also zeroes the
// S/V accumulators and the completion counter (ws is re-poisoned per iter).
__global__ __launch_bounds__(256) void prep_kernel(
        const float* __restrict__ feat, _Float16* __restrict__ M,
        float* __restrict__ S, float* __restrict__ V,
        int* __restrict__ counter) {
    int r = blockIdx.x;
    int k = threadIdx.x;
    float x = feat[r * Dq + k];
    float ss = waveReduceSum(x * x);
    __shared__ float wsum[4];
    int wid = k >> 6, lane = k & 63;
    if (lane == 0) wsum[wid] = ss;
    __syncthreads();
    float n = fmaxf(sqrtf(wsum[0] + wsum[1] + wsum[2] + wsum[3]), 1e-12f);
    float a = x / n;
    float a2 = a * a, a3 = a2 * a, a4 = a2 * a2;
    float c1 = a * (1.0f + a3);
    float c2 = (1.0f + a3) * (1.0f + a3);
    int o = r * Dq + k;
    _Float16 h, l;
    split16(c1, &h, &l); M[0 * MS + o] = h; M[1 * MS + o] = l;
    split16(c2, &h, &l); M[2 * MS + o] = h; M[3 * MS + o] = l;
    split16(a,  &h, &l); M[4 * MS + o] = h; M[5 * MS + o] = l;
    split16(a2, &h, &l); M[6 * MS + o] = h; M[7 * MS + o] = l;
    M[8 * MS + o] = (_Float16)a3;
    M[9 * MS + o] = (_Float16)(a4 * 64.0f);
    if (r == 0) {
        S[k] = 0.f; S[k + 256] = 0.f;
        V[k] = 0.f; V[k + 256] = 0.f;
        if (k == 0) *counter = 0;
    }
}

// Kernel 2: split-fp16 MFMA GEMM (R6 structure, unchanged math) + fused
// last-block finale. Finale uses ONLY relaxed atomics; ordering is by
// per-wave s_waitcnt vmcnt(0) after the S/V atomicAdds (completion at the
// coherent point) — no ACQ_REL/RELEASE fences (R2's +9.5us buffer_wbl2 storm).
__global__ __launch_bounds__(256) void pairmm_kernel(
        const _Float16* __restrict__ M,
        float* __restrict__ S, float* __restrict__ V,
        int* __restrict__ counter, float* __restrict__ out) {
    const int t = threadIdx.x;
    const int w = t >> 6, lane = t & 63;
    const int lr = lane & 15, lg = lane >> 4;
    const int bx = blockIdx.x;
    const int it = (bx >> 4) * 32 + (w >> 1) * 16;
    const int jt = (bx & 15) * 32 + (w & 1) * 16;
    const int offi = (it + lr) * Dq + lg * 8;
    const int offj = (jt + lr) * Dq + lg * 8;

    const _Float16* __restrict__ C1h = M;
    const _Float16* __restrict__ C1l = M + 1 * MS;
    const _Float16* __restrict__ C2h = M + 2 * MS;
    const _Float16* __restrict__ C2l = M + 3 * MS;
    const _Float16* __restrict__ Ah  = M + 4 * MS;
    const _Float16* __restrict__ Al  = M + 5 * MS;
    const _Float16* __restrict__ A2h = M + 6 * MS;
    const _Float16* __restrict__ A2l = M + 7 * MS;
    const _Float16* __restrict__ A3h = M + 8 * MS;
    const _Float16* __restrict__ A4h = M + 9 * MS;

    f32x4 du = {0.f, 0.f, 0.f, 0.f};
    f32x4 nu = {0.f, 0.f, 0.f, 0.f};
    f32x4 dv = {0.f, 0.f, 0.f, 0.f};
    f32x4 n3 = {0.f, 0.f, 0.f, 0.f};
    f32x4 n4 = {0.f, 0.f, 0.f, 0.f};

    #pragma unroll 2
    for (int kk = 0; kk < Dq; kk += 32) {
        int oi = offi + kk, oj = offj + kk;
        f16x8 c1h = *(const f16x8*)(C1h + oi);
        f16x8 c1l = *(const f16x8*)(C1l + oi);
        f16x8 c2h = *(const f16x8*)(C2h + oi);
        f16x8 c2l = *(const f16x8*)(C2l + oi);
        f16x8 ahi = *(const f16x8*)(Ah  + oi);
        f16x8 ali = *(const f16x8*)(Al  + oi);
        f16x8 a2i = *(const f16x8*)(A2h + oi);
        f16x8 a3i = *(const f16x8*)(A3h + oi);
        f16x8 a4i = *(const f16x8*)(A4h + oi);
        f16x8 ahj = *(const f16x8*)(Ah  + oj);
        f16x8 alj = *(const f16x8*)(Al  + oj);
        f16x8 a2j = *(const f16x8*)(A2h + oj);
        f16x8 a2lj = *(const f16x8*)(A2l + oj);
        f16x8 a3j = *(const f16x8*)(A3h + oj);
        f16x8 a4j = *(const f16x8*)(A4h + oj);

        du = __builtin_amdgcn_mfma_f32_16x16x32_f16(c1h, ahj,  du, 0, 0, 0);
        du = __builtin_amdgcn_mfma_f32_16x16x32_f16(c1h, alj,  du, 0, 0, 0);
        du = __builtin_amdgcn_mfma_f32_16x16x32_f16(c1l, ahj,  du, 0, 0, 0);
        nu = __builtin_amdgcn_mfma_f32_16x16x32_f16(c2h, a2j,  nu, 0, 0, 0);
        nu = __builtin_amdgcn_mfma_f32_16x16x32_f16(c2h, a2lj, nu, 0, 0, 0);
        nu = __builtin_amdgcn_mfma_f32_16x16x32_f16(c2l, a2j,  nu, 0, 0, 0);
        dv = __builtin_amdgcn_mfma_f32_16x16x32_f16(ahi, ahj,  dv, 0, 0, 0);
        dv = __builtin_amdgcn_mfma_f32_16x16x32_f16(ahi, alj,  dv, 0, 0, 0);
        dv = __builtin_amdgcn_mfma_f32_16x16x32_f16(ali, ahj,  dv, 0, 0, 0);
        dv = __builtin_amdgcn_mfma_f32_16x16x32_f16(a3i, a2j,  dv, 0, 0, 0);
        n3 = __builtin_amdgcn_mfma_f32_16x16x32_f16(a2i, a3j,  n3, 0, 0, 0);
        n4 = __builtin_amdgcn_mfma_f32_16x16x32_f16(a4i, a4j,  n4, 0, 0, 0);
    }

    const float Tinv = 1.0f / 0.07f;
    float sS[4], sV[4];
    #pragma unroll
    for (int r = 0; r < 4; ++r) {
        float nuv = fmaxf(nu[r], 0.f);
        float nvv = fmaxf(1.0f + 2.0f * n3[r] + n4[r] * (1.0f / 4096.0f), 0.f);
        float raw_s = du[r] / fmaxf(sqrtf(nuv), 1e-12f) * Tinv;
        float raw_o = dv[r] / fmaxf(sqrtf(nvv), 1e-12f) * Tinv;
        int gi = it + lg * 4 + r;
        int gj = jt + lr;
        sS[r] = raw_s;
        sV[r] = (gi == gj) ? 0.f : (expf(raw_s) + 3.0f * expf(raw_o));
    }
    #pragma unroll
    for (int r = 0; r < 4; ++r) {
        #pragma unroll
        for (int m = 1; m < 16; m <<= 1) {
            sS[r] += __shfl_xor(sS[r], m, 64);
            sV[r] += __shfl_xor(sV[r], m, 64);
        }
    }
    if (lr == 0) {
        #pragma unroll
        for (int r = 0; r < 4; ++r) {
            atomicAdd(&S[it + lg * 4 + r], sS[r]);
            atomicAdd(&V[it + lg * 4 + r], sV[r]);
        }
    }

    // --- fused finale (last-block pattern, relaxed-only) ---
    asm volatile("s_waitcnt vmcnt(0)" ::: "memory");  // this wave's adds complete
    __syncthreads();                                   // all waves' adds complete
    __shared__ int s_last;
    if (t == 0) {
        int old = __hip_atomic_fetch_add(counter, 1, __ATOMIC_RELAXED,
                                         __HIP_MEMORY_SCOPE_AGENT);
        s_last = (old == 255) ? 1 : 0;
    }
    __syncthreads();
    if (s_last) {
        // all 256 blocks' device-scope atomicAdds are complete => visible
        float Sa = __hip_atomic_load(&S[t],       __ATOMIC_RELAXED, __HIP_MEMORY_SCOPE_AGENT);
        float Va = __hip_atomic_load(&V[t],       __ATOMIC_RELAXED, __HIP_MEMORY_SCOPE_AGENT);
        float Sb = __hip_atomic_load(&S[t + 256], __ATOMIC_RELAXED, __HIP_MEMORY_SCOPE_AGENT);
        float Vb = __hip_atomic_load(&V[t + 256], __ATOMIC_RELAXED, __HIP_MEMORY_SCOPE_AGENT);
        float v = (Sa * (1.0f / Bq) - logf(Va)) + (Sb * (1.0f / Bq) - logf(Vb));
        v = waveReduceSum(v);
        __shared__ float red[4];
        if (lane == 0) red[w] = v;
        __syncthreads();
        if (t == 0)
            out[0] = -(red[0] + red[1] + red[2] + red[3]) / (float)Bq;
    }
}

extern "C" void kernel_launch(void* const* d_in, const int* in_sizes, int n_in,
                              void* d_out, int out_size, void* d_ws, size_t ws_size,
                              hipStream_t stream) {
    const float* feat = (const float*)d_in[0];
    _Float16* M = (_Float16*)d_ws;                       // 10 * MS halves = 2.62 MB
    float* S = (float*)((char*)d_ws + (size_t)10 * MS * sizeof(_Float16));
    float* V = S + Bq;
    int* counter = (int*)(V + Bq);

    prep_kernel<<<Bq, Dq, 0, stream>>>(feat, M, S, V, counter);
    pairmm_kernel<<<256, 256, 0, stream>>>(M, S, V, counter, (float*)d_out);
}